// Round 8
// baseline (5527.428 us; speedup 1.0000x reference)
//
#include <hip/hip_runtime.h>
#include <hip/hip_bf16.h>
#include <math.h>

#define Tt 80
#define Vv 10000
#define Ee 100
#define Uu 512
#define ROWS 16
#define NBLK 256

typedef __attribute__((ext_vector_type(8))) short short8;
typedef __attribute__((ext_vector_type(4))) float f32x4;
typedef __attribute__((ext_vector_type(4))) unsigned u32x4;

__device__ __forceinline__ unsigned short f2bf(float f) {
    union { float f; unsigned u; } x{f};
    unsigned u = x.u;
    return (unsigned short)((u + 0x7fffu + ((u >> 16) & 1u)) >> 16);
}

// branch-free tanh via exp; clamp keeps e finite; no libcall
__device__ __forceinline__ float tanh_fast(float x) {
    float z = fminf(fmaxf(x, -15.f), 15.f);
    float e = __expf(2.f * z);
    return (e - 1.f) / (e + 1.f);
}

// assemble an MFMA B-fragment from 4 pinned 32-bit scalars (all indices static)
__device__ __forceinline__ short8 mk8(unsigned a, unsigned b, unsigned c, unsigned d) {
    union { unsigned u[4]; short8 s; } p;
    p.u[0] = a; p.u[1] = b; p.u[2] = c; p.u[3] = d;
    return p.s;
}

// ---------------- P1: embW0 = emb@W0 + b0 (fp32, exact input term; 20MB, L3) ----------------
__global__ __launch_bounds__(512) void k_embw0(const float* __restrict__ emb,
                                               const float* __restrict__ W0,
                                               const float* __restrict__ b0,
                                               float* __restrict__ embW0) {
    __shared__ float semb[4][Ee];
    int v0 = blockIdx.x * 4;
    int tid = threadIdx.x;
    if (tid < 4 * Ee) semb[tid / Ee][tid % Ee] = emb[(v0 + tid / Ee) * Ee + tid % Ee];
    __syncthreads();
    float b = b0[tid];
    for (int vl = 0; vl < 4; ++vl) {
        float a = 0.f;
        #pragma unroll 4
        for (int e = 0; e < Ee; ++e) a += semb[vl][e] * W0[e * Uu + tid];
        embW0[(v0 + vl) * Uu + tid] = a + b;
    }
}

// ---------------- P2: pack U0, W1/U1 into 48 slice-major 32KB K-slices ----------------
// S<16: U0 ks=S.  S>=16: s2=S-16, ks=s2>>1, mat=(s2&1)?U1:W1.
// element addr (short8 units): (S*32 + ntg)*64 + lane ;
// frag[j] = M[ks*32 + 8*(lane>>4) + j][ntg*16 + (lane&15)]
__global__ __launch_bounds__(256) void k_pack(const float* __restrict__ U0,
                                              const float* __restrict__ W1,
                                              const float* __restrict__ U1,
                                              unsigned short* __restrict__ pW) {
    int gid = blockIdx.x * 256 + threadIdx.x;   // 0 .. 98303 (48 * 32 * 64)
    int S = gid >> 11;
    int ntg = (gid >> 6) & 31;
    int lane = gid & 63;
    const float* src;
    int ks;
    if (S < 16) { src = U0; ks = S; }
    else { int s2 = S - 16; ks = s2 >> 1; src = (s2 & 1) ? U1 : W1; }
    int row0 = ks * 32 + (lane >> 4) * 8;
    int col = ntg * 16 + (lane & 15);
    short8 v;
    #pragma unroll
    for (int j = 0; j < 8; ++j) v[j] = (short)f2bf(src[(row0 + j) * Uu + col]);
    *(short8*)(pW + (size_t)gid * 8) = v;
}

// ---------------- main RNN: weights register-resident via 32-bit scalar pins ----------------
// U0 -> 128 pinned VGPR scalars; W1,U1 -> 256 pinned AGPR scalars.
__global__ __launch_bounds__(1024, 4)
void k_rnn(const int* __restrict__ tokens,
           const float* __restrict__ embW0,
           const unsigned short* __restrict__ pWu,
           const float* __restrict__ b1,
           const float* __restrict__ Wout,
           const float* __restrict__ bout,
           float* __restrict__ out) {
    __shared__ __align__(16) char smem[32768 + ROWS * Tt * 4];
    char* h0b = smem;                    // bf16 [16][512] swizzled, 16KB
    char* h1b = smem + 16384;            // bf16 [16][512] swizzled, 16KB
    int* stok = (int*)(smem + 32768);    // [16][80] tokens
    float* finalb = (float*)smem;        // fp32 [16][512] overlay for epilogue

    const int tid = threadIdx.x;
    const int lane = tid & 63;
    const int wv = tid >> 6;             // 0..15, owns cols wv*32 .. wv*32+31
    const int q = lane >> 4;
    const int ln = lane & 15;
    const int bbase = blockIdx.x * ROWS;
    const int swz = (ln & 7) << 4;

    // zero h buffers (32KB)
    {
        uint4 z = {0u, 0u, 0u, 0u};
        for (int i = tid; i < 2048; i += 1024) ((uint4*)smem)[i] = z;
    }
    // stage tokens
    for (int i = tid; i < ROWS * Tt; i += 1024) stok[i] = tokens[bbase * Tt + i];

    // -------- load this wave's weight slice; pin every 32-bit piece --------
    const u32x4* pf = (const u32x4*)pWu;
    unsigned wU0[16][2][4], wW1[16][2][4], wU1[16][2][4];
    #pragma unroll
    for (int ks = 0; ks < 16; ++ks) {
        #pragma unroll
        for (int j = 0; j < 2; ++j) {
            int ntg = wv * 2 + j;
            u32x4 v0 = pf[((size_t)ks * 32 + ntg) * 64 + lane];
            u32x4 v1 = pf[((size_t)(16 + 2 * ks) * 32 + ntg) * 64 + lane];
            u32x4 v2 = pf[((size_t)(17 + 2 * ks) * 32 + ntg) * 64 + lane];
            #pragma unroll
            for (int c = 0; c < 4; ++c) {
                wU0[ks][j][c] = v0[c];
                asm volatile("" : "+v"(wU0[ks][j][c]));
                wW1[ks][j][c] = v1[c];
                asm volatile("" : "+a"(wW1[ks][j][c]));
                wU1[ks][j][c] = v2[c];
                asm volatile("" : "+a"(wU1[ks][j][c]));
            }
        }
    }

    float b1c[2];
    #pragma unroll
    for (int n = 0; n < 2; ++n) b1c[n] = b1[wv * 32 + n * 16 + ln];
    float boutv = bout[0];

    __syncthreads();   // h zeros + stok visible

    // prefetch input-term gathers for t=0
    float gx[2][4];
    #pragma unroll
    for (int r = 0; r < 4; ++r) {
        int tk = stok[(q * 4 + r) * Tt + 0];
        #pragma unroll
        for (int n = 0; n < 2; ++n)
            gx[n][r] = embW0[(size_t)tk * Uu + wv * 32 + n * 16 + ln];
    }

    for (int t = 0; t < Tt; ++t) {
        // ---------- layer 0: th0 = tanh(gather + h0_old @ U0) ----------
        f32x4 acc0[2];
        #pragma unroll
        for (int n = 0; n < 2; ++n)
            #pragma unroll
            for (int r = 0; r < 4; ++r) acc0[n][r] = 0.f;
        #pragma unroll
        for (int ks = 0; ks < 16; ++ks) {
            short8 a = *(const short8*)(h0b + ((ln * 1024 + ks * 64 + q * 16) ^ swz));
            acc0[0] = __builtin_amdgcn_mfma_f32_16x16x32_bf16(
                a, mk8(wU0[ks][0][0], wU0[ks][0][1], wU0[ks][0][2], wU0[ks][0][3]), acc0[0], 0, 0, 0);
            acc0[1] = __builtin_amdgcn_mfma_f32_16x16x32_bf16(
                a, mk8(wU0[ks][1][0], wU0[ks][1][1], wU0[ks][1][2], wU0[ks][1][3]), acc0[1], 0, 0, 0);
        }
        float th0[2][4];
        #pragma unroll
        for (int n = 0; n < 2; ++n)
            #pragma unroll
            for (int r = 0; r < 4; ++r) th0[n][r] = tanh_fast(acc0[n][r] + gx[n][r]);

        __syncthreads();   // all waves done reading old h0
        #pragma unroll
        for (int n = 0; n < 2; ++n)
            #pragma unroll
            for (int r = 0; r < 4; ++r) {
                int row = q * 4 + r;
                int col = wv * 32 + n * 16 + ln;
                *(unsigned short*)(h0b + ((row * 1024 + col * 2) ^ ((row & 7) << 4))) = f2bf(th0[n][r]);
            }
        __syncthreads();   // new h0 visible

        // ---------- layer 1: th1 = tanh(b1 + h0_new @ W1 + h1_old @ U1) ----------
        // prefetch next step's gathers (hidden under the 64-MFMA loop)
        if (t + 1 < Tt) {
            #pragma unroll
            for (int r = 0; r < 4; ++r) {
                int tk = stok[(q * 4 + r) * Tt + t + 1];
                #pragma unroll
                for (int n = 0; n < 2; ++n)
                    gx[n][r] = embW0[(size_t)tk * Uu + wv * 32 + n * 16 + ln];
            }
        }
        f32x4 acc1[2];
        #pragma unroll
        for (int n = 0; n < 2; ++n)
            #pragma unroll
            for (int r = 0; r < 4; ++r) acc1[n][r] = b1c[n];
        #pragma unroll
        for (int ks = 0; ks < 16; ++ks) {
            int byteA = (ln * 1024 + ks * 64 + q * 16) ^ swz;
            short8 a0 = *(const short8*)(h0b + byteA);
            short8 a1 = *(const short8*)(h1b + byteA);
            acc1[0] = __builtin_amdgcn_mfma_f32_16x16x32_bf16(
                a0, mk8(wW1[ks][0][0], wW1[ks][0][1], wW1[ks][0][2], wW1[ks][0][3]), acc1[0], 0, 0, 0);
            acc1[1] = __builtin_amdgcn_mfma_f32_16x16x32_bf16(
                a0, mk8(wW1[ks][1][0], wW1[ks][1][1], wW1[ks][1][2], wW1[ks][1][3]), acc1[1], 0, 0, 0);
            acc1[0] = __builtin_amdgcn_mfma_f32_16x16x32_bf16(
                a1, mk8(wU1[ks][0][0], wU1[ks][0][1], wU1[ks][0][2], wU1[ks][0][3]), acc1[0], 0, 0, 0);
            acc1[1] = __builtin_amdgcn_mfma_f32_16x16x32_bf16(
                a1, mk8(wU1[ks][1][0], wU1[ks][1][1], wU1[ks][1][2], wU1[ks][1][3]), acc1[1], 0, 0, 0);
        }
        float th1[2][4];
        #pragma unroll
        for (int n = 0; n < 2; ++n)
            #pragma unroll
            for (int r = 0; r < 4; ++r) th1[n][r] = tanh_fast(acc1[n][r]);

        __syncthreads();   // all waves done reading old h1
        if (t < Tt - 1) {
            #pragma unroll
            for (int n = 0; n < 2; ++n)
                #pragma unroll
                for (int r = 0; r < 4; ++r) {
                    int row = q * 4 + r;
                    int col = wv * 32 + n * 16 + ln;
                    *(unsigned short*)(h1b + ((row * 1024 + col * 2) ^ ((row & 7) << 4))) = f2bf(th1[n][r]);
                }
        } else {
            #pragma unroll
            for (int n = 0; n < 2; ++n)
                #pragma unroll
                for (int r = 0; r < 4; ++r)
                    finalb[(q * 4 + r) * Uu + wv * 32 + n * 16 + ln] = th1[n][r];
        }
        __syncthreads();   // writes visible
    }

    // ---------------- epilogue: wave wv -> batch row wv ----------------
    float s = 0.f;
    #pragma unroll
    for (int j = 0; j < 8; ++j)
        s += finalb[wv * Uu + lane * 8 + j] * Wout[lane * 8 + j];
    #pragma unroll
    for (int off = 32; off; off >>= 1) s += __shfl_xor(s, off);
    if (lane == 0) out[bbase + wv] = 1.f / (1.f + __expf(-(s + boutv)));
}

extern "C" void kernel_launch(void* const* d_in, const int* in_sizes, int n_in,
                              void* d_out, int out_size, void* d_ws, size_t ws_size,
                              hipStream_t stream) {
    const int*   tokens = (const int*)d_in[0];
    const float* emb    = (const float*)d_in[1];
    const float* W0     = (const float*)d_in[2];
    const float* U0     = (const float*)d_in[3];
    const float* b0     = (const float*)d_in[4];
    const float* W1     = (const float*)d_in[5];
    const float* U1     = (const float*)d_in[6];
    const float* b1     = (const float*)d_in[7];
    const float* Wout   = (const float*)d_in[8];
    const float* bout   = (const float*)d_in[9];
    float* outp = (float*)d_out;

    char* ws = (char*)d_ws;
    float* embW0 = (float*)ws;                                   // 20,480,000 B
    unsigned short* pW = (unsigned short*)(ws + 20480000);       // 48*32KB = 1,572,864 B

    hipLaunchKernelGGL(k_embw0, dim3(Vv / 4), dim3(512), 0, stream, emb, W0, b0, embW0);
    hipLaunchKernelGGL(k_pack, dim3(384), dim3(256), 0, stream, U0, W1, U1, pW);
    hipLaunchKernelGGL(k_rnn, dim3(NBLK), dim3(1024), 0, stream,
                       tokens, embW0, pW, b1, Wout, bout, outp);
}

// Round 9
// 5375.623 us; speedup vs baseline: 1.0282x; 1.0282x over previous
//
#include <hip/hip_runtime.h>
#include <hip/hip_bf16.h>
#include <math.h>

#define Tt 80
#define Vv 10000
#define Ee 100
#define Uu 512
#define ROWS 32
#define NBLK 128
#define SLICE_B 32768
#define NSLICE 48

typedef __attribute__((ext_vector_type(8))) short short8;
typedef __attribute__((ext_vector_type(4))) float f32x4;

__device__ __forceinline__ unsigned short f2bf(float f) {
    union { float f; unsigned u; } x{f};
    unsigned u = x.u;
    return (unsigned short)((u + 0x7fffu + ((u >> 16) & 1u)) >> 16);
}

// branch-free tanh via exp; clamp keeps e finite
__device__ __forceinline__ float tanh_fast(float x) {
    float z = fminf(fmaxf(x, -15.f), 15.f);
    float e = __expf(2.f * z);
    return (e - 1.f) / (e + 1.f);
}

// ---------------- P1: embW0 = emb@W0 + b0 (fp32, exact input term; 20MB, L3) ----------------
__global__ __launch_bounds__(512) void k_embw0(const float* __restrict__ emb,
                                               const float* __restrict__ W0,
                                               const float* __restrict__ b0,
                                               float* __restrict__ embW0) {
    __shared__ float semb[4][Ee];
    int v0 = blockIdx.x * 4;
    int tid = threadIdx.x;
    if (tid < 4 * Ee) semb[tid / Ee][tid % Ee] = emb[(v0 + tid / Ee) * Ee + tid % Ee];
    __syncthreads();
    float b = b0[tid];
    for (int vl = 0; vl < 4; ++vl) {
        float a = 0.f;
        #pragma unroll 4
        for (int e = 0; e < Ee; ++e) a += semb[vl][e] * W0[e * Uu + tid];
        embW0[(v0 + vl) * Uu + tid] = a + b;
    }
}

// ---------------- P2: pack U0, W1/U1 into 48 slice-major 32KB K-slices ----------------
// S<16: U0 ks=S.  S>=16: s2=S-16, ks=s2>>1, mat=(s2&1)?U1:W1.
// Within slice: [(ntg*64 + lane)*8 + j] = M[ks*32 + 8*(lane>>4) + j][ntg*16 + (lane&15)]
__global__ __launch_bounds__(256) void k_pack(const float* __restrict__ U0,
                                              const float* __restrict__ W1,
                                              const float* __restrict__ U1,
                                              unsigned short* __restrict__ pW) {
    int gid = blockIdx.x * 256 + threadIdx.x;   // 0 .. 98303 (48 * 32 * 64)
    int S = gid >> 11;
    int ntg = (gid >> 6) & 31;
    int lane = gid & 63;
    const float* src;
    int ks;
    if (S < 16) { src = U0; ks = S; }
    else { int s2 = S - 16; ks = s2 >> 1; src = (s2 & 1) ? U1 : W1; }
    int row0 = ks * 32 + (lane >> 4) * 8;
    int col = ntg * 16 + (lane & 15);
    short8 v;
    #pragma unroll
    for (int j = 0; j < 8; ++j) v[j] = (short)f2bf(src[(row0 + j) * Uu + col]);
    *(short8*)(pW + (size_t)gid * 8) = v;
}

// ---------------- main RNN kernel: 3-slot ring, depth-2 prefetch ----------------
__device__ __forceinline__ void stage4(const char* gs, char* ld, int wv, int lane) {
    #pragma unroll
    for (int k2 = 0; k2 < 4; ++k2)
        __builtin_amdgcn_global_load_lds(
            (const __attribute__((address_space(1))) void*)(gs + (wv * 4 + k2) * 1024 + lane * 16),
            (__attribute__((address_space(3))) void*)(ld + (wv * 4 + k2) * 1024),
            16, 0, 0);
}

#define VM_SYNC() do { asm volatile("s_waitcnt vmcnt(4)" ::: "memory"); \
    __builtin_amdgcn_sched_barrier(0); __builtin_amdgcn_s_barrier(); \
    __builtin_amdgcn_sched_barrier(0); } while (0)
#define LG_SYNC() do { asm volatile("s_waitcnt lgkmcnt(0)" ::: "memory"); \
    __builtin_amdgcn_sched_barrier(0); __builtin_amdgcn_s_barrier(); \
    __builtin_amdgcn_sched_barrier(0); } while (0)

__global__ __launch_bounds__(512) void k_rnn(const int* __restrict__ tokens,
                                             const float* __restrict__ embW0,
                                             const unsigned short* __restrict__ pWu,
                                             const float* __restrict__ b1,
                                             const float* __restrict__ Wout,
                                             const float* __restrict__ bout,
                                             float* __restrict__ out) {
    __shared__ __align__(16) char smem[163840];
    char* h0b = smem;                  // bf16 [32][512] swizzled, 32KB
    char* h1b = smem + 32768;          // bf16 [32][512] swizzled, 32KB
    char* ring = smem + 65536;         // 3 x 32KB staging ring
    float* finalb = (float*)ring;      // fp32 [32][512] overlay for epilogue (64KB <= 96KB)

    const int tid = threadIdx.x;
    const int lane = tid & 63;
    const int wv = tid >> 6;           // 0..7, owns cols wv*64 .. wv*64+63 (ntg wv*4..wv*4+3)
    const int q = lane >> 4;
    const int ln = lane & 15;
    const int bbase = blockIdx.x * ROWS;
    const int swz = (ln & 7) << 4;
    const char* pW = (const char*)pWu;

    // zero h buffers (64KB)
    {
        uint4 z = {0u, 0u, 0u, 0u};
        for (int i = tid; i < 4096; i += 512) ((uint4*)smem)[i] = z;
    }
    __syncthreads();

    // prologue: fill slots 0,1 with slices 0,1 (depth-2 steady state)
    stage4(pW + 0 * SLICE_B, ring + 0 * SLICE_B, wv, lane);
    stage4(pW + 1 * SLICE_B, ring + 1 * SLICE_B, wv, lane);

    float b1c[4];
    #pragma unroll
    for (int n = 0; n < 4; ++n) b1c[n] = b1[wv * 64 + n * 16 + ln];
    float wout8[8];
    #pragma unroll
    for (int j = 0; j < 8; ++j) wout8[j] = Wout[lane * 8 + j];
    float boutv = bout[0];

    f32x4 th1[2][4];   // persists across steps

    for (int t = 0; t < Tt; ++t) {
        f32x4 acc0[2][4];

        // ---------------- layer 0: 16 phases (slices 0..15 = U0) ----------------
        #pragma unroll
        for (int S = 0; S < 16; ++S) {
            VM_SYNC();   // slice S arrived (vmcnt(4): S+1, in flight); barrier frees slot (S+2)%3
            if (S == 0 && t > 0) {
                #pragma unroll
                for (int m = 0; m < 2; ++m)
                    #pragma unroll
                    for (int n = 0; n < 4; ++n)
                        #pragma unroll
                        for (int r = 0; r < 4; ++r) {
                            int row = m * 16 + q * 4 + r;
                            int col = wv * 64 + n * 16 + ln;
                            *(unsigned short*)(h1b + ((row * 1024 + col * 2) ^ ((row & 7) << 4)))
                                = f2bf(th1[m][n][r]);
                        }
                LG_SYNC();
            }
            // issue slice S+2 into slot (S+2)%3 (freed by the barrier above)
            stage4(pW + ((S + 2) % NSLICE) * SLICE_B, ring + ((S + 2) % 3) * SLICE_B, wv, lane);
            if (S == 0) {
                // input-term gather init (exact fp32; once per step)
                #pragma unroll
                for (int m = 0; m < 2; ++m)
                    #pragma unroll
                    for (int r = 0; r < 4; ++r) {
                        int tk = tokens[(bbase + m * 16 + q * 4 + r) * Tt + t];
                        #pragma unroll
                        for (int n = 0; n < 4; ++n)
                            acc0[m][n][r] = __builtin_nontemporal_load(
                                &embW0[(size_t)tk * Uu + wv * 64 + n * 16 + ln]);
                    }
            }
            const char* rs = ring + (S % 3) * SLICE_B;
            short8 bfr[4];
            #pragma unroll
            for (int n = 0; n < 4; ++n)
                bfr[n] = *(const short8*)(rs + ((wv * 4 + n) * 64 + lane) * 16);
            #pragma unroll
            for (int m = 0; m < 2; ++m) {
                short8 afr = *(const short8*)(h0b + (((m * 16 + ln) * 1024 + S * 64 + q * 16) ^ swz));
                #pragma unroll
                for (int n = 0; n < 4; ++n)
                    acc0[m][n] = __builtin_amdgcn_mfma_f32_16x16x32_bf16(afr, bfr[n], acc0[m][n], 0, 0, 0);
            }
        }

        f32x4 th0[2][4];
        #pragma unroll
        for (int m = 0; m < 2; ++m)
            #pragma unroll
            for (int n = 0; n < 4; ++n)
                #pragma unroll
                for (int r = 0; r < 4; ++r) th0[m][n][r] = tanh_fast(acc0[m][n][r]);

        // ---------------- layer 1: 32 phases (slices 16..47 = W1/U1 interleaved) ----------------
        f32x4 acc1[2][4];
        #pragma unroll
        for (int m = 0; m < 2; ++m)
            #pragma unroll
            for (int n = 0; n < 4; ++n)
                #pragma unroll
                for (int r = 0; r < 4; ++r) acc1[m][n][r] = b1c[n];

        #pragma unroll
        for (int k2 = 0; k2 < 16; ++k2) {
            // ---- W1 phase: S = 16 + 2*k2 ----
            {
                const int S = 16 + 2 * k2;
                if (t == Tt - 1 && S == 46) { /* keep uniform wait */ }
                VM_SYNC();
                if (k2 == 0) {
                    #pragma unroll
                    for (int m = 0; m < 2; ++m)
                        #pragma unroll
                        for (int n = 0; n < 4; ++n)
                            #pragma unroll
                            for (int r = 0; r < 4; ++r) {
                                int row = m * 16 + q * 4 + r;
                                int col = wv * 64 + n * 16 + ln;
                                *(unsigned short*)(h0b + ((row * 1024 + col * 2) ^ ((row & 7) << 4)))
                                    = f2bf(th0[m][n][r]);
                            }
                    LG_SYNC();
                }
                stage4(pW + ((S + 2) % NSLICE) * SLICE_B, ring + ((S + 2) % 3) * SLICE_B, wv, lane);
                const char* rs = ring + (S % 3) * SLICE_B;
                short8 bfr[4];
                #pragma unroll
                for (int n = 0; n < 4; ++n)
                    bfr[n] = *(const short8*)(rs + ((wv * 4 + n) * 64 + lane) * 16);
                #pragma unroll
                for (int m = 0; m < 2; ++m) {
                    short8 aw = *(const short8*)(h0b + (((m * 16 + ln) * 1024 + k2 * 64 + q * 16) ^ swz));
                    #pragma unroll
                    for (int n = 0; n < 4; ++n)
                        acc1[m][n] = __builtin_amdgcn_mfma_f32_16x16x32_bf16(aw, bfr[n], acc1[m][n], 0, 0, 0);
                }
            }
            // ---- U1 phase: S = 17 + 2*k2 ----
            {
                const int S = 17 + 2 * k2;
                VM_SYNC();
                stage4(pW + ((S + 2) % NSLICE) * SLICE_B, ring + ((S + 2) % 3) * SLICE_B, wv, lane);
                const char* rs = ring + (S % 3) * SLICE_B;
                short8 bfr[4];
                #pragma unroll
                for (int n = 0; n < 4; ++n)
                    bfr[n] = *(const short8*)(rs + ((wv * 4 + n) * 64 + lane) * 16);
                #pragma unroll
                for (int m = 0; m < 2; ++m) {
                    short8 au = *(const short8*)(h1b + (((m * 16 + ln) * 1024 + k2 * 64 + q * 16) ^ swz));
                    #pragma unroll
                    for (int n = 0; n < 4; ++n)
                        acc1[m][n] = __builtin_amdgcn_mfma_f32_16x16x32_bf16(au, bfr[n], acc1[m][n], 0, 0, 0);
                }
            }
        }

        #pragma unroll
        for (int m = 0; m < 2; ++m)
            #pragma unroll
            for (int n = 0; n < 4; ++n)
                #pragma unroll
                for (int r = 0; r < 4; ++r) th1[m][n][r] = tanh_fast(acc1[m][n][r]);
    }

    // ---------------- epilogue ----------------
    asm volatile("s_waitcnt vmcnt(0) lgkmcnt(0)" ::: "memory");
    __builtin_amdgcn_sched_barrier(0);
    __builtin_amdgcn_s_barrier();
    __builtin_amdgcn_sched_barrier(0);

    #pragma unroll
    for (int m = 0; m < 2; ++m)
        #pragma unroll
        for (int n = 0; n < 4; ++n)
            #pragma unroll
            for (int r = 0; r < 4; ++r)
                finalb[(m * 16 + q * 4 + r) * Uu + wv * 64 + n * 16 + ln] = th1[m][n][r];
    LG_SYNC();

    // out[row] = sigmoid(h1[row,:] @ Wout + bout); wave wv -> rows wv*4 .. wv*4+3
    #pragma unroll
    for (int rr = 0; rr < 4; ++rr) {
        int row = wv * 4 + rr;
        float s = 0.f;
        #pragma unroll
        for (int j = 0; j < 8; ++j)
            s += finalb[row * Uu + lane * 8 + j] * wout8[j];
        #pragma unroll
        for (int off = 32; off; off >>= 1) s += __shfl_xor(s, off);
        if (lane == 0) out[bbase + row] = 1.f / (1.f + __expf(-(s + boutv)));
    }
}

extern "C" void kernel_launch(void* const* d_in, const int* in_sizes, int n_in,
                              void* d_out, int out_size, void* d_ws, size_t ws_size,
                              hipStream_t stream) {
    const int*   tokens = (const int*)d_in[0];
    const float* emb    = (const float*)d_in[1];
    const float* W0     = (const float*)d_in[2];
    const float* U0     = (const float*)d_in[3];
    const float* b0     = (const float*)d_in[4];
    const float* W1     = (const float*)d_in[5];
    const float* U1     = (const float*)d_in[6];
    const float* b1     = (const float*)d_in[7];
    const float* Wout   = (const float*)d_in[8];
    const float* bout   = (const float*)d_in[9];
    float* outp = (float*)d_out;

    char* ws = (char*)d_ws;
    float* embW0 = (float*)ws;                                   // 20,480,000 B
    unsigned short* pW = (unsigned short*)(ws + 20480000);       // 48*32KB = 1,572,864 B

    hipLaunchKernelGGL(k_embw0, dim3(Vv / 4), dim3(512), 0, stream, emb, W0, b0, embW0);
    hipLaunchKernelGGL(k_pack, dim3(384), dim3(256), 0, stream, U0, W1, U1, pW);
    hipLaunchKernelGGL(k_rnn, dim3(NBLK), dim3(512), 0, stream,
                       tokens, embW0, pW, b1, Wout, bout, outp);
}